// Round 1
// 439.304 us; speedup vs baseline: 1.0643x; 1.0643x over previous
//
#include <hip/hip_runtime.h>

#define N_NODES 100000
#define N_EDGES 1600000
#define NGROUPS 8
#define NODES_PER_GROUP 12500   // N_NODES / NGROUPS
#define SCAN_BLOCKS 25          // 25 * 4096 = 102400 >= N_NODES

// ---------------------------------------------------------------------------
// CSR build (rebuilt every launch; ws is re-poisoned between calls).
// ---------------------------------------------------------------------------
__global__ __launch_bounds__(1024) void k_zero(int* __restrict__ cnt) {
    int i = blockIdx.x * 1024 + threadIdx.x;
    if (i < N_NODES) cnt[i] = 0;
}

__global__ __launch_bounds__(256) void k_count(const int* __restrict__ ei,
                                               int* __restrict__ cnt) {
    int e = blockIdx.x * 256 + threadIdx.x;
    if (e < N_EDGES) atomicAdd(&cnt[ei[N_EDGES + e]], 1);
}

// Hierarchical scan, stage 1: each block scans a 4096-elem chunk (4/thread),
// writes chunk-local EXCLUSIVE scan to off[] and its chunk total to bsum[].
__global__ __launch_bounds__(1024) void k_scan_local(const int* __restrict__ cnt,
                                                     int* __restrict__ off,
                                                     int* __restrict__ bsum) {
    __shared__ int waveSums[16];
    const int tid  = threadIdx.x;
    const int lane = tid & 63;
    const int wid  = tid >> 6;
    const int base = blockIdx.x * 4096 + tid * 4;
    int v0 = 0, v1 = 0, v2 = 0, v3 = 0;
    const bool inR = (base < N_NODES);          // N_NODES % 4 == 0: all-or-none
    if (inR) { int4 q = *(const int4*)&cnt[base]; v0 = q.x; v1 = q.y; v2 = q.z; v3 = q.w; }
    int s = v0 + v1 + v2 + v3;
    int incl = s;
    #pragma unroll
    for (int d = 1; d < 64; d <<= 1) {
        int n = __shfl_up(incl, d, 64);
        if (lane >= d) incl += n;
    }
    if (lane == 63) waveSums[wid] = incl;
    __syncthreads();
    int waveOff = 0, total = 0;
    #pragma unroll
    for (int w = 0; w < 16; ++w) {
        int ws = waveSums[w];
        waveOff += (w < wid) ? ws : 0;
        total   += ws;
    }
    if (inR) {
        int e0 = waveOff + incl - s;            // chunk-local exclusive
        int4 o = {e0, e0 + v0, e0 + v0 + v1, e0 + v0 + v1 + v2};
        *(int4*)&off[base] = o;
    }
    if (tid == 0) bsum[blockIdx.x] = total;
}

// Stage 2: add chunk base (redundant mini-scan of bsum per block), finalize
// off[] and copy to cnt[] as permute cursors. off[N_NODES] is the known total.
__global__ __launch_bounds__(1024) void k_scan_fix(int* __restrict__ off,
                                                   int* __restrict__ cnt,
                                                   const int* __restrict__ bsum) {
    const int b = blockIdx.x;
    int add = 0;
    for (int j = 0; j < b; ++j) add += bsum[j];
    const int base = b * 4096 + threadIdx.x * 4;
    if (base < N_NODES) {
        int4 q = *(int4*)&off[base];
        q.x += add; q.y += add; q.z += add; q.w += add;
        *(int4*)&off[base] = q;
        *(int4*)&cnt[base] = q;
    }
    if (b == 0 && threadIdx.x == 0) off[N_NODES] = N_EDGES;
}

// XCD-partitioned permute: group g = blockIdx&7 handles only dst in its
// 12500-node range, so each group's srcS writes land in one contiguous 1/8
// slice (~0.8 MB, L2-resident). 8x redundant dst reads are LLC-absorbed.
__global__ __launch_bounds__(256) void k_permute(const int* __restrict__ ei,
                                                 int* __restrict__ cursor,
                                                 int* __restrict__ srcS) {
    const int g     = blockIdx.x & 7;
    const int slice = blockIdx.x >> 3;
    const int lo    = g * NODES_PER_GROUP;
    const int hi    = lo + NODES_PER_GROUP;
    const int e0    = slice * 1280;             // 1250 slices * 1280 = 1.6M exact
    #pragma unroll
    for (int i = 0; i < 5; ++i) {
        int e   = e0 + i * 256 + threadIdx.x;
        int dst = ei[N_EDGES + e];
        if (dst >= lo && dst < hi) {
            int src = ei[e];
            int pos = atomicAdd(&cursor[dst], 1);
            srcS[pos] = src;
        }
    }
}

// ---------------------------------------------------------------------------
// Gather-aggregate: z[n] = y[n] + sum_{e: dst==n} y[src_e].  One wave per
// node, lane == channel (64 ch). No atomics.
// MLP version: one coalesced srcS load per 64 edges, __shfl broadcast of the
// indices, 8 independent row-gathers in flight per iteration.
// ---------------------------------------------------------------------------
__global__ __launch_bounds__(256) void k_gather_agg(const int* __restrict__ off,
                                                    const int* __restrict__ srcS,
                                                    const float* __restrict__ y,
                                                    float* __restrict__ z) {
    const int node = blockIdx.x * 4 + (threadIdx.x >> 6);
    if (node >= N_NODES) return;
    const int lane = threadIdx.x & 63;
    const int beg = off[node];
    const int end = off[node + 1];
    float acc = y[((size_t)node << 6) + lane];
    int i = beg;
    while (i < end) {
        const int rem  = end - i;
        const int take = rem < 64 ? rem : 64;
        int idx = i + lane;
        if (idx > end - 1) idx = end - 1;       // in-range duplicate for lanes >= take
        const int sv = srcS[idx];               // coalesced: 64 edge indices / wave
        int j = 0;
        for (; j + 8 <= take; j += 8) {
            const int s0 = __shfl(sv, j + 0), s1 = __shfl(sv, j + 1);
            const int s2 = __shfl(sv, j + 2), s3 = __shfl(sv, j + 3);
            const int s4 = __shfl(sv, j + 4), s5 = __shfl(sv, j + 5);
            const int s6 = __shfl(sv, j + 6), s7 = __shfl(sv, j + 7);
            const float v0 = y[((size_t)s0 << 6) + lane];
            const float v1 = y[((size_t)s1 << 6) + lane];
            const float v2 = y[((size_t)s2 << 6) + lane];
            const float v3 = y[((size_t)s3 << 6) + lane];
            const float v4 = y[((size_t)s4 << 6) + lane];
            const float v5 = y[((size_t)s5 << 6) + lane];
            const float v6 = y[((size_t)s6 << 6) + lane];
            const float v7 = y[((size_t)s7 << 6) + lane];
            acc += ((v0 + v1) + (v2 + v3)) + ((v4 + v5) + (v6 + v7));
        }
        for (; j < take; ++j) {
            const int s = __shfl(sv, j);
            acc += y[((size_t)s << 6) + lane];
        }
        i += take;
    }
    z[((size_t)node << 6) + lane] = acc;
}

// ---------------------------------------------------------------------------
// K1: y = x @ W1  (N x 128 @ 128 x 64).  64x64 block tile, 4x4 register tile
// per thread, X staged TRANSPOSED in LDS (stride 68 keeps 16B alignment).
// Per k-step per wave: 2 ds_read_b128 for 16 FMAs (vs 2 reads / 4 FMAs before).
// ---------------------------------------------------------------------------
#define FMA16()                                                       \
    do {                                                              \
        acc0.x += a.x * w.x; acc0.y += a.x * w.y;                     \
        acc0.z += a.x * w.z; acc0.w += a.x * w.w;                     \
        acc1.x += a.y * w.x; acc1.y += a.y * w.y;                     \
        acc1.z += a.y * w.z; acc1.w += a.y * w.w;                     \
        acc2.x += a.z * w.x; acc2.y += a.z * w.y;                     \
        acc2.z += a.z * w.z; acc2.w += a.z * w.w;                     \
        acc3.x += a.w * w.x; acc3.y += a.w * w.y;                     \
        acc3.z += a.w * w.z; acc3.w += a.w * w.w;                     \
    } while (0)

__global__ __launch_bounds__(256) void k_mm1(const float* __restrict__ x,
                                             const float* __restrict__ W1,
                                             float* __restrict__ y) {
    __shared__ float sW[128 * 64];    // 32 KB, [k][n]
    __shared__ float sxT[128 * 68];   // 34 KB, [k][m] transposed, stride 68
    const int tid  = threadIdx.x;
    const int row0 = blockIdx.x * 64;
    #pragma unroll
    for (int i = tid * 4; i < 128 * 64; i += 1024)
        *(float4*)&sW[i] = *(const float4*)&W1[i];
    #pragma unroll 8
    for (int i = tid; i < 64 * 128; i += 256) {
        int m = i >> 7, k = i & 127;                 // coalesced in k
        int r = row0 + m; if (r >= N_NODES) r = N_NODES - 1;
        sxT[k * 68 + m] = x[(size_t)r * 128 + k];
    }
    __syncthreads();
    const int tx = tid & 15;          // cols tx*4 .. +3
    const int ty = tid >> 4;          // rows ty*4 .. +3
    float4 acc0 = {0.f,0.f,0.f,0.f}, acc1 = {0.f,0.f,0.f,0.f};
    float4 acc2 = {0.f,0.f,0.f,0.f}, acc3 = {0.f,0.f,0.f,0.f};
    #pragma unroll 4
    for (int k = 0; k < 128; ++k) {
        float4 a = *(const float4*)&sxT[k * 68 + ty * 4];
        float4 w = *(const float4*)&sW[k * 64 + tx * 4];
        FMA16();
    }
    const int rb = row0 + ty * 4;
    if (rb + 0 < N_NODES) *(float4*)&y[(size_t)(rb + 0) * 64 + tx * 4] = acc0;
    if (rb + 1 < N_NODES) *(float4*)&y[(size_t)(rb + 1) * 64 + tx * 4] = acc1;
    if (rb + 2 < N_NODES) *(float4*)&y[(size_t)(rb + 2) * 64 + tx * 4] = acc2;
    if (rb + 3 < N_NODES) *(float4*)&y[(size_t)(rb + 3) * 64 + tx * 4] = acc3;
}

// ---------------------------------------------------------------------------
// K3: h1 = relu(z1 + b1);  y2 = h1 @ W2  (64x64).  Same register-tiled scheme.
// ---------------------------------------------------------------------------
__global__ __launch_bounds__(256) void k_relu_mm2(const float* __restrict__ z1,
                                                  const float* __restrict__ b1,
                                                  const float* __restrict__ W2,
                                                  float* __restrict__ y2) {
    __shared__ float sW[64 * 64];     // 16 KB, [k][n]
    __shared__ float shT[64 * 68];    // 17 KB, [k][m] transposed
    const int tid  = threadIdx.x;
    const int row0 = blockIdx.x * 64;
    #pragma unroll
    for (int i = tid * 4; i < 64 * 64; i += 1024)
        *(float4*)&sW[i] = *(const float4*)&W2[i];
    #pragma unroll 8
    for (int i = tid; i < 64 * 64; i += 256) {
        int m = i >> 6, k = i & 63;                  // coalesced in k
        int r = row0 + m; if (r >= N_NODES) r = N_NODES - 1;
        shT[k * 68 + m] = fmaxf(z1[(size_t)r * 64 + k] + b1[k], 0.f);
    }
    __syncthreads();
    const int tx = tid & 15;
    const int ty = tid >> 4;
    float4 acc0 = {0.f,0.f,0.f,0.f}, acc1 = {0.f,0.f,0.f,0.f};
    float4 acc2 = {0.f,0.f,0.f,0.f}, acc3 = {0.f,0.f,0.f,0.f};
    #pragma unroll 4
    for (int k = 0; k < 64; ++k) {
        float4 a = *(const float4*)&shT[k * 68 + ty * 4];
        float4 w = *(const float4*)&sW[k * 64 + tx * 4];
        FMA16();
    }
    const int rb = row0 + ty * 4;
    if (rb + 0 < N_NODES) *(float4*)&y2[(size_t)(rb + 0) * 64 + tx * 4] = acc0;
    if (rb + 1 < N_NODES) *(float4*)&y2[(size_t)(rb + 1) * 64 + tx * 4] = acc1;
    if (rb + 2 < N_NODES) *(float4*)&y2[(size_t)(rb + 2) * 64 + tx * 4] = acc2;
    if (rb + 3 < N_NODES) *(float4*)&y2[(size_t)(rb + 3) * 64 + tx * 4] = acc3;
}

// ---------------------------------------------------------------------------
// K5: per-node tail: h2 = relu(z2+b2); h3 = relu(h2@W3+b3); out = h3@W4+b4.
// ---------------------------------------------------------------------------
__global__ __launch_bounds__(256) void k_tail(const float* __restrict__ z2,
                                              const float* __restrict__ b2,
                                              const float* __restrict__ W3,
                                              const float* __restrict__ b3,
                                              const float* __restrict__ W4,
                                              const float* __restrict__ b4,
                                              float* __restrict__ out) {
    __shared__ float sW3[64 * 16];
    __shared__ float sW4[16];
    __shared__ float sb3[16];
    const int tid = threadIdx.x;
    *(float4*)&sW3[tid * 4] = *(const float4*)&W3[tid * 4];
    if (tid < 16) { sW4[tid] = W4[tid]; sb3[tid] = b3[tid]; }
    __syncthreads();
    const int node = blockIdx.x * 256 + tid;
    if (node >= N_NODES) return;

    float h[64];
    const float4* zp = (const float4*)&z2[(size_t)node * 64];
    #pragma unroll
    for (int i = 0; i < 16; ++i) {
        float4 v  = zp[i];
        float4 bb = *(const float4*)&b2[i * 4];
        h[i * 4 + 0] = fmaxf(v.x + bb.x, 0.f);
        h[i * 4 + 1] = fmaxf(v.y + bb.y, 0.f);
        h[i * 4 + 2] = fmaxf(v.z + bb.z, 0.f);
        h[i * 4 + 3] = fmaxf(v.w + bb.w, 0.f);
    }
    float acc[16];
    #pragma unroll
    for (int j = 0; j < 16; ++j) acc[j] = sb3[j];
    #pragma unroll 8
    for (int k = 0; k < 64; ++k) {
        float hv = h[k];
        #pragma unroll
        for (int j = 0; j < 16; ++j) acc[j] += hv * sW3[k * 16 + j];
    }
    float o = b4[0];
    #pragma unroll
    for (int j = 0; j < 16; ++j) o += fmaxf(acc[j], 0.f) * sW4[j];
    out[node] = o;
}

extern "C" void kernel_launch(void* const* d_in, const int* in_sizes, int n_in,
                              void* d_out, int out_size, void* d_ws, size_t ws_size,
                              hipStream_t stream) {
    const float* x  = (const float*)d_in[0];
    const int*   ei = (const int*)d_in[1];
    const float* W1 = (const float*)d_in[2];
    const float* b1 = (const float*)d_in[3];
    const float* W2 = (const float*)d_in[4];
    const float* b2 = (const float*)d_in[5];
    const float* W3 = (const float*)d_in[6];
    const float* b3 = (const float*)d_in[7];
    const float* W4 = (const float*)d_in[8];
    const float* b4 = (const float*)d_in[9];
    float* out = (float*)d_out;

    // ws layout: y | z | cnt/cursor | off | srcSorted | bsum
    float* bufA = (float*)d_ws;
    float* bufB = bufA + (size_t)N_NODES * 64;
    int*   cnt  = (int*)(bufB + (size_t)N_NODES * 64);
    int*   off  = cnt + N_NODES;
    int*   srcS = off + N_NODES + 4;          // keep 16B alignment slack
    int*   bsum = srcS + N_EDGES;

    const int edgeBlocks = (N_EDGES + 255) / 256;     // 6250
    const int permBlocks = 1250 * NGROUPS;            // 10000
    const int mmBlocks   = (N_NODES + 63) / 64;       // 1563
    const int aggBlocks  = (N_NODES + 3) / 4;         // 25000
    const int tailBlocks = (N_NODES + 255) / 256;     // 391

    // CSR build (once per launch, used by both convs)
    k_zero<<<(N_NODES + 1023) / 1024, 1024, 0, stream>>>(cnt);
    k_count<<<edgeBlocks, 256, 0, stream>>>(ei, cnt);
    k_scan_local<<<SCAN_BLOCKS, 1024, 0, stream>>>(cnt, off, bsum);
    k_scan_fix<<<SCAN_BLOCKS, 1024, 0, stream>>>(off, cnt, bsum);
    k_permute<<<permBlocks, 256, 0, stream>>>(ei, cnt, srcS);

    // conv1: y1 = x@W1 ; z1 = y1 + gather-sum(y1)
    k_mm1<<<mmBlocks, 256, 0, stream>>>(x, W1, bufA);
    k_gather_agg<<<aggBlocks, 256, 0, stream>>>(off, srcS, bufA, bufB);
    // conv2: y2 = relu(z1+b1)@W2 ; z2 = y2 + gather-sum(y2)
    k_relu_mm2<<<mmBlocks, 256, 0, stream>>>(bufB, b1, W2, bufA);
    k_gather_agg<<<aggBlocks, 256, 0, stream>>>(off, srcS, bufA, bufB);
    // head
    k_tail<<<tailBlocks, 256, 0, stream>>>(bufB, b2, W3, b3, W4, b4, out);
}

// Round 2
// 390.729 us; speedup vs baseline: 1.1966x; 1.1243x over previous
//
#include <hip/hip_runtime.h>

#define N_NODES 100000
#define N_EDGES 1600000
#define SCAN_BLOCKS 25          // 25 * 4096 = 102400 >= N_NODES

// ---------------------------------------------------------------------------
// CSR build (rebuilt every launch; ws is re-poisoned between calls).
// Scheme: pos[e] = rank of edge e within its dst (captured during the fused
// mm1+count kernel), then scan, then an atomic-free scatter.
// ---------------------------------------------------------------------------
__global__ __launch_bounds__(1024) void k_zero(int* __restrict__ cnt) {
    int i = blockIdx.x * 1024 + threadIdx.x;
    if (i < N_NODES) cnt[i] = 0;
}

// Hierarchical scan, stage 1: each block scans a 4096-elem chunk (4/thread),
// writes chunk-local EXCLUSIVE scan to off[] and its chunk total to bsum[].
__global__ __launch_bounds__(1024) void k_scan_local(const int* __restrict__ cnt,
                                                     int* __restrict__ off,
                                                     int* __restrict__ bsum) {
    __shared__ int waveSums[16];
    const int tid  = threadIdx.x;
    const int lane = tid & 63;
    const int wid  = tid >> 6;
    const int base = blockIdx.x * 4096 + tid * 4;
    int v0 = 0, v1 = 0, v2 = 0, v3 = 0;
    const bool inR = (base < N_NODES);          // N_NODES % 4 == 0: all-or-none
    if (inR) { int4 q = *(const int4*)&cnt[base]; v0 = q.x; v1 = q.y; v2 = q.z; v3 = q.w; }
    int s = v0 + v1 + v2 + v3;
    int incl = s;
    #pragma unroll
    for (int d = 1; d < 64; d <<= 1) {
        int n = __shfl_up(incl, d, 64);
        if (lane >= d) incl += n;
    }
    if (lane == 63) waveSums[wid] = incl;
    __syncthreads();
    int waveOff = 0, total = 0;
    #pragma unroll
    for (int w = 0; w < 16; ++w) {
        int ws = waveSums[w];
        waveOff += (w < wid) ? ws : 0;
        total   += ws;
    }
    if (inR) {
        int e0 = waveOff + incl - s;            // chunk-local exclusive
        int4 o = {e0, e0 + v0, e0 + v0 + v1, e0 + v0 + v1 + v2};
        *(int4*)&off[base] = o;
    }
    if (tid == 0) bsum[blockIdx.x] = total;
}

// Stage 2: add chunk base (redundant mini-scan of bsum per block), finalize
// off[]. off[N_NODES] is the known total.
__global__ __launch_bounds__(1024) void k_scan_fix(int* __restrict__ off,
                                                   const int* __restrict__ bsum) {
    const int b = blockIdx.x;
    int add = 0;
    for (int j = 0; j < b; ++j) add += bsum[j];
    const int base = b * 4096 + threadIdx.x * 4;
    if (base < N_NODES) {
        int4 q = *(int4*)&off[base];
        q.x += add; q.y += add; q.z += add; q.w += add;
        *(int4*)&off[base] = q;
    }
    if (b == 0 && threadIdx.x == 0) off[N_NODES] = N_EDGES;
}

// Atomic-free scatter: srcS[off[dst[e]] + pos[e]] = src[e].
// Coalesced dst/src/pos streams (LLC-warm), off gather hits the 400 KB
// L2-resident table, scattered 4B payload writes (no atomics, 1x reads).
__global__ __launch_bounds__(256) void k_scatter(const int* __restrict__ ei,
                                                 const int* __restrict__ pos,
                                                 const int* __restrict__ off,
                                                 int* __restrict__ srcS) {
    const int e0 = (blockIdx.x * 256 + threadIdx.x) * 4;
    if (e0 >= N_EDGES) return;                 // N_EDGES % 4 == 0: all-or-none
    int4 d4 = *(const int4*)&ei[N_EDGES + e0];
    int4 s4 = *(const int4*)&ei[e0];
    int4 p4 = *(const int4*)&pos[e0];
    srcS[off[d4.x] + p4.x] = s4.x;
    srcS[off[d4.y] + p4.y] = s4.y;
    srcS[off[d4.z] + p4.z] = s4.z;
    srcS[off[d4.w] + p4.w] = s4.w;
}

// ---------------------------------------------------------------------------
// Gather-aggregate: z[n] = y[n] + sum_{e: dst==n} y[src_e].  One wave per
// node, lane == channel (64 ch). One coalesced srcS load per 64 edges,
// __shfl broadcast of indices, 8 independent row-gathers in flight.
// ---------------------------------------------------------------------------
__global__ __launch_bounds__(256) void k_gather_agg(const int* __restrict__ off,
                                                    const int* __restrict__ srcS,
                                                    const float* __restrict__ y,
                                                    float* __restrict__ z) {
    const int node = blockIdx.x * 4 + (threadIdx.x >> 6);
    if (node >= N_NODES) return;
    const int lane = threadIdx.x & 63;
    const int beg = off[node];
    const int end = off[node + 1];
    float acc = y[((size_t)node << 6) + lane];
    int i = beg;
    while (i < end) {
        const int rem  = end - i;
        const int take = rem < 64 ? rem : 64;
        int idx = i + lane;
        if (idx > end - 1) idx = end - 1;       // in-range duplicate for lanes >= take
        const int sv = srcS[idx];               // coalesced: 64 edge indices / wave
        int j = 0;
        for (; j + 8 <= take; j += 8) {
            const int s0 = __shfl(sv, j + 0), s1 = __shfl(sv, j + 1);
            const int s2 = __shfl(sv, j + 2), s3 = __shfl(sv, j + 3);
            const int s4 = __shfl(sv, j + 4), s5 = __shfl(sv, j + 5);
            const int s6 = __shfl(sv, j + 6), s7 = __shfl(sv, j + 7);
            const float v0 = y[((size_t)s0 << 6) + lane];
            const float v1 = y[((size_t)s1 << 6) + lane];
            const float v2 = y[((size_t)s2 << 6) + lane];
            const float v3 = y[((size_t)s3 << 6) + lane];
            const float v4 = y[((size_t)s4 << 6) + lane];
            const float v5 = y[((size_t)s5 << 6) + lane];
            const float v6 = y[((size_t)s6 << 6) + lane];
            const float v7 = y[((size_t)s7 << 6) + lane];
            acc += ((v0 + v1) + (v2 + v3)) + ((v4 + v5) + (v6 + v7));
        }
        for (; j < take; ++j) {
            const int s = __shfl(sv, j);
            acc += y[((size_t)s << 6) + lane];
        }
        i += take;
    }
    z[((size_t)node << 6) + lane] = acc;
}

// ---------------------------------------------------------------------------
// K1 (fused): y = x @ W1  (N x 128 @ 128 x 64), 64x64 block tile, 4x4
// register tile; ALSO counts in-degrees for a 1024-edge chunk: the atomics
// are issued right after the staging barrier and their latency hides under
// the 128-deep FMA loop; pos[] results stored at the end.
// ---------------------------------------------------------------------------
#define FMA16()                                                       \
    do {                                                              \
        acc0.x += a.x * w.x; acc0.y += a.x * w.y;                     \
        acc0.z += a.x * w.z; acc0.w += a.x * w.w;                     \
        acc1.x += a.y * w.x; acc1.y += a.y * w.y;                     \
        acc1.z += a.y * w.z; acc1.w += a.y * w.w;                     \
        acc2.x += a.z * w.x; acc2.y += a.z * w.y;                     \
        acc2.z += a.z * w.z; acc2.w += a.z * w.w;                     \
        acc3.x += a.w * w.x; acc3.y += a.w * w.y;                     \
        acc3.z += a.w * w.z; acc3.w += a.w * w.w;                     \
    } while (0)

__global__ __launch_bounds__(256) void k_mm1_count(const float* __restrict__ x,
                                                   const float* __restrict__ W1,
                                                   const int* __restrict__ ei,
                                                   int* __restrict__ cnt,
                                                   int* __restrict__ pos,
                                                   float* __restrict__ y) {
    __shared__ float sW[128 * 64];    // 32 KB, [k][n]
    __shared__ float sxT[128 * 68];   // 34 KB, [k][m] transposed, stride 68
    const int tid  = threadIdx.x;
    const int row0 = blockIdx.x * 64;

    // Edge chunk for this block: 1024 edges, 4/thread (N_EDGES % 4 == 0).
    const int e0   = blockIdx.x * 1024 + tid * 4;
    const bool eok = (e0 < N_EDGES);
    int4 d4 = {0, 0, 0, 0};
    if (eok) d4 = *(const int4*)&ei[N_EDGES + e0];

    #pragma unroll
    for (int i = tid * 4; i < 128 * 64; i += 1024)
        *(float4*)&sW[i] = *(const float4*)&W1[i];
    #pragma unroll 8
    for (int i = tid; i < 64 * 128; i += 256) {
        int m = i >> 7, k = i & 127;                 // coalesced in k
        int r = row0 + m; if (r >= N_NODES) r = N_NODES - 1;
        sxT[k * 68 + m] = x[(size_t)r * 128 + k];
    }
    __syncthreads();

    // Issue the ranking atomics now; results not needed until after the FMAs.
    int4 p4 = {0, 0, 0, 0};
    if (eok) {
        p4.x = atomicAdd(&cnt[d4.x], 1);
        p4.y = atomicAdd(&cnt[d4.y], 1);
        p4.z = atomicAdd(&cnt[d4.z], 1);
        p4.w = atomicAdd(&cnt[d4.w], 1);
    }

    const int tx = tid & 15;          // cols tx*4 .. +3
    const int ty = tid >> 4;          // rows ty*4 .. +3
    float4 acc0 = {0.f,0.f,0.f,0.f}, acc1 = {0.f,0.f,0.f,0.f};
    float4 acc2 = {0.f,0.f,0.f,0.f}, acc3 = {0.f,0.f,0.f,0.f};
    #pragma unroll 4
    for (int k = 0; k < 128; ++k) {
        float4 a = *(const float4*)&sxT[k * 68 + ty * 4];
        float4 w = *(const float4*)&sW[k * 64 + tx * 4];
        FMA16();
    }
    const int rb = row0 + ty * 4;
    if (rb + 0 < N_NODES) *(float4*)&y[(size_t)(rb + 0) * 64 + tx * 4] = acc0;
    if (rb + 1 < N_NODES) *(float4*)&y[(size_t)(rb + 1) * 64 + tx * 4] = acc1;
    if (rb + 2 < N_NODES) *(float4*)&y[(size_t)(rb + 2) * 64 + tx * 4] = acc2;
    if (rb + 3 < N_NODES) *(float4*)&y[(size_t)(rb + 3) * 64 + tx * 4] = acc3;

    if (eok) *(int4*)&pos[e0] = p4;
}

// ---------------------------------------------------------------------------
// K3: h1 = relu(z1 + b1);  y2 = h1 @ W2  (64x64).  Same register-tiled scheme.
// ---------------------------------------------------------------------------
__global__ __launch_bounds__(256) void k_relu_mm2(const float* __restrict__ z1,
                                                  const float* __restrict__ b1,
                                                  const float* __restrict__ W2,
                                                  float* __restrict__ y2) {
    __shared__ float sW[64 * 64];     // 16 KB, [k][n]
    __shared__ float shT[64 * 68];    // 17 KB, [k][m] transposed
    const int tid  = threadIdx.x;
    const int row0 = blockIdx.x * 64;
    #pragma unroll
    for (int i = tid * 4; i < 64 * 64; i += 1024)
        *(float4*)&sW[i] = *(const float4*)&W2[i];
    #pragma unroll 8
    for (int i = tid; i < 64 * 64; i += 256) {
        int m = i >> 6, k = i & 63;                  // coalesced in k
        int r = row0 + m; if (r >= N_NODES) r = N_NODES - 1;
        shT[k * 68 + m] = fmaxf(z1[(size_t)r * 64 + k] + b1[k], 0.f);
    }
    __syncthreads();
    const int tx = tid & 15;
    const int ty = tid >> 4;
    float4 acc0 = {0.f,0.f,0.f,0.f}, acc1 = {0.f,0.f,0.f,0.f};
    float4 acc2 = {0.f,0.f,0.f,0.f}, acc3 = {0.f,0.f,0.f,0.f};
    #pragma unroll 4
    for (int k = 0; k < 64; ++k) {
        float4 a = *(const float4*)&shT[k * 68 + ty * 4];
        float4 w = *(const float4*)&sW[k * 64 + tx * 4];
        FMA16();
    }
    const int rb = row0 + ty * 4;
    if (rb + 0 < N_NODES) *(float4*)&y2[(size_t)(rb + 0) * 64 + tx * 4] = acc0;
    if (rb + 1 < N_NODES) *(float4*)&y2[(size_t)(rb + 1) * 64 + tx * 4] = acc1;
    if (rb + 2 < N_NODES) *(float4*)&y2[(size_t)(rb + 2) * 64 + tx * 4] = acc2;
    if (rb + 3 < N_NODES) *(float4*)&y2[(size_t)(rb + 3) * 64 + tx * 4] = acc3;
}

// ---------------------------------------------------------------------------
// K5: per-node tail: h2 = relu(z2+b2); h3 = relu(h2@W3+b3); out = h3@W4+b4.
// ---------------------------------------------------------------------------
__global__ __launch_bounds__(256) void k_tail(const float* __restrict__ z2,
                                              const float* __restrict__ b2,
                                              const float* __restrict__ W3,
                                              const float* __restrict__ b3,
                                              const float* __restrict__ W4,
                                              const float* __restrict__ b4,
                                              float* __restrict__ out) {
    __shared__ float sW3[64 * 16];
    __shared__ float sW4[16];
    __shared__ float sb3[16];
    const int tid = threadIdx.x;
    *(float4*)&sW3[tid * 4] = *(const float4*)&W3[tid * 4];
    if (tid < 16) { sW4[tid] = W4[tid]; sb3[tid] = b3[tid]; }
    __syncthreads();
    const int node = blockIdx.x * 256 + tid;
    if (node >= N_NODES) return;

    float h[64];
    const float4* zp = (const float4*)&z2[(size_t)node * 64];
    #pragma unroll
    for (int i = 0; i < 16; ++i) {
        float4 v  = zp[i];
        float4 bb = *(const float4*)&b2[i * 4];
        h[i * 4 + 0] = fmaxf(v.x + bb.x, 0.f);
        h[i * 4 + 1] = fmaxf(v.y + bb.y, 0.f);
        h[i * 4 + 2] = fmaxf(v.z + bb.z, 0.f);
        h[i * 4 + 3] = fmaxf(v.w + bb.w, 0.f);
    }
    float acc[16];
    #pragma unroll
    for (int j = 0; j < 16; ++j) acc[j] = sb3[j];
    #pragma unroll 8
    for (int k = 0; k < 64; ++k) {
        float hv = h[k];
        #pragma unroll
        for (int j = 0; j < 16; ++j) acc[j] += hv * sW3[k * 16 + j];
    }
    float o = b4[0];
    #pragma unroll
    for (int j = 0; j < 16; ++j) o += fmaxf(acc[j], 0.f) * sW4[j];
    out[node] = o;
}

extern "C" void kernel_launch(void* const* d_in, const int* in_sizes, int n_in,
                              void* d_out, int out_size, void* d_ws, size_t ws_size,
                              hipStream_t stream) {
    const float* x  = (const float*)d_in[0];
    const int*   ei = (const int*)d_in[1];
    const float* W1 = (const float*)d_in[2];
    const float* b1 = (const float*)d_in[3];
    const float* W2 = (const float*)d_in[4];
    const float* b2 = (const float*)d_in[5];
    const float* W3 = (const float*)d_in[6];
    const float* b3 = (const float*)d_in[7];
    const float* W4 = (const float*)d_in[8];
    const float* b4 = (const float*)d_in[9];
    float* out = (float*)d_out;

    // ws layout: bufA | bufB | cnt | off | srcSorted | bsum
    // pos[] aliases bufB: written by k_mm1_count, consumed by k_scatter,
    // both strictly before the first k_gather_agg overwrites bufB with z1.
    float* bufA = (float*)d_ws;
    float* bufB = bufA + (size_t)N_NODES * 64;
    int*   cnt  = (int*)(bufB + (size_t)N_NODES * 64);
    int*   off  = cnt + N_NODES;
    int*   srcS = off + N_NODES + 4;          // keep 16B alignment slack
    int*   bsum = srcS + N_EDGES;
    int*   pos  = (int*)bufB;

    const int mmBlocks   = (N_NODES + 63) / 64;       // 1563 (also covers 1.6M edges)
    const int scatBlocks = (N_EDGES / 4 + 255) / 256; // 1563
    const int aggBlocks  = (N_NODES + 3) / 4;         // 25000
    const int tailBlocks = (N_NODES + 255) / 256;     // 391

    // CSR build interleaved with conv1's matmul.
    k_zero<<<(N_NODES + 1023) / 1024, 1024, 0, stream>>>(cnt);
    k_mm1_count<<<mmBlocks, 256, 0, stream>>>(x, W1, ei, cnt, pos, bufA);
    k_scan_local<<<SCAN_BLOCKS, 1024, 0, stream>>>(cnt, off, bsum);
    k_scan_fix<<<SCAN_BLOCKS, 1024, 0, stream>>>(off, bsum);
    k_scatter<<<scatBlocks, 256, 0, stream>>>(ei, pos, off, srcS);

    // conv1 aggregate: z1 = y1 + gather-sum(y1)   (overwrites pos region)
    k_gather_agg<<<aggBlocks, 256, 0, stream>>>(off, srcS, bufA, bufB);
    // conv2: y2 = relu(z1+b1)@W2 ; z2 = y2 + gather-sum(y2)
    k_relu_mm2<<<mmBlocks, 256, 0, stream>>>(bufB, b1, W2, bufA);
    k_gather_agg<<<aggBlocks, 256, 0, stream>>>(off, srcS, bufA, bufB);
    // head
    k_tail<<<tailBlocks, 256, 0, stream>>>(bufB, b2, W3, b3, W4, b4, out);
}